// Round 7
// baseline (473.105 us; speedup 1.0000x reference)
//
#include <hip/hip_runtime.h>
#include <hip/hip_cooperative_groups.h>

#define CDIM 128
#define NGRAPH 256
#define BSH 7                 // 128 nodes per bucket
#define BCAP 4096             // LDS sort capacity (mean 2048, +45 sigma)
#define NBLK 256              // blocks for sort chain
#define TILE 6272             // >= ceil(E/NBLK) = 6250

typedef unsigned short bf16_t;
typedef __attribute__((ext_vector_type(8))) short bf16x8;  // MFMA A/B frag (4 VGPRs)
typedef __attribute__((ext_vector_type(4))) float f32x4;   // MFMA C/D frag

__device__ __forceinline__ float bflo(unsigned u) { return __uint_as_float(u << 16); }
__device__ __forceinline__ float bfhi(unsigned u) { return __uint_as_float(u & 0xffff0000u); }
__device__ __forceinline__ unsigned short f2bf(float f) {
  unsigned u = __float_as_uint(f);
  u += 0x7fffu + ((u >> 16) & 1u);   // round-to-nearest-even
  return (unsigned short)(u >> 16);
}

// ---------- fused sort chain (cooperative): phist -> bscan -> pscatter -> csort
// One kernel, 4 phases, grid.sync() between. 256 blocks x 1024 thr, 1 block/CU
// co-resident (54KB LDS). Phase arithmetic identical to the R6 split kernels.
union SortLds {
  struct { int hist[1024]; } a;
  struct { int wsum[16]; } b;
  struct { int lh[1024]; int ls[1024]; int lc[1024]; int gb2[1024];
           unsigned short sbkt[TILE]; unsigned sbuf[TILE]; } c;
  struct { int hist[128]; int sc[128]; int lcur[128]; int red[1024];
           unsigned buf[BCAP]; } d;
};

__global__ __launch_bounds__(1024) void k_sort(
    const int* __restrict__ src, const int* __restrict__ dst,
    int* __restrict__ phist, int* __restrict__ btot, unsigned* __restrict__ tmp,
    const float* __restrict__ W1, const float* __restrict__ W2,
    bf16_t* __restrict__ Wtg1, bf16_t* __restrict__ Wtg2,
    float* __restrict__ gb, bf16_t* __restrict__ tz1, bf16_t* __restrict__ tz2,
    int* __restrict__ rowptr, float* __restrict__ dinv, int* __restrict__ col,
    int N, int E, int NB) {
  __shared__ SortLds S;
  cooperative_groups::grid_group gg = cooperative_groups::this_grid();
  int t = blockIdx.x, tid = threadIdx.x;
  int lane = tid & 63, wave = tid >> 6;
  int tile = (E + NBLK - 1) / NBLK;

  // ---- phase A: prologue + per-block bucket histogram ----
  int gidx = t * 1024 + tid;
  if (gidx < 16384) {                       // W transpose->bf16 (blocks 0..15)
    int n = gidx >> 7, k = gidx & 127;
    Wtg1[n * 128 + k] = f2bf(W1[k * 128 + n]);
    Wtg2[n * 128 + k] = f2bf(W2[k * 128 + n]);
  }
  if (gidx < NGRAPH * CDIM) gb[gidx] = 0.f; // gb zero
  if (gidx < 64) {                          // zero pad row N (fake-edge target)
    ((unsigned*)(tz1 + (size_t)N * CDIM))[gidx] = 0u;
    ((unsigned*)(tz2 + (size_t)N * CDIM))[gidx] = 0u;
  }
  for (int i = tid; i < NB; i += 1024) S.a.hist[i] = 0;
  __syncthreads();
  {
    int lo = t * tile;
    int hi = lo + tile; if (hi > E) hi = E;
    for (int i = lo + tid; i < hi; i += 1024) atomicAdd(&S.a.hist[dst[i] >> BSH], 1);
  }
  __syncthreads();
  for (int i = tid; i < NB; i += 1024) phist[i * NBLK + t] = S.a.hist[i];
  gg.sync();

  // ---- phase B: per-bucket scan of phist rows (exclusive in place) + btot ----
  for (int bk = t; bk < NB; bk += NBLK) {
    int orig = (tid < NBLK) ? phist[bk * NBLK + tid] : 0;
    int v = orig;
#pragma unroll
    for (int ofs = 1; ofs < 64; ofs <<= 1) {
      int u = __shfl_up(v, ofs, 64);
      if (lane >= ofs) v += u;
    }
    if (lane == 63 && wave < 4) S.b.wsum[wave] = v;
    __syncthreads();
    int add = 0;
#pragma unroll
    for (int w = 0; w < 3; w++) if (w < wave) add += S.b.wsum[w];
    int incl = v + add;
    if (tid < NBLK) phist[bk * NBLK + tid] = incl - orig;
    if (tid == 255) btot[bk] = incl;
    __syncthreads();
  }
  gg.sync();

  // ---- phase C: LDS local counting sort + run-coalesced scatter to tmp ----
  {
    int v = (tid < NB) ? btot[tid] : 0;
    S.c.ls[tid] = v;
    __syncthreads();
    for (int ofs = 1; ofs < 1024; ofs <<= 1) {
      int u = (tid >= ofs) ? S.c.ls[tid - ofs] : 0;
      __syncthreads();
      S.c.ls[tid] += u;
      __syncthreads();
    }
    if (tid < NB) S.c.gb2[tid] = (S.c.ls[tid] - v) + phist[tid * NBLK + t];
    S.c.lh[tid] = 0;
    __syncthreads();

    int lo = t * tile;
    int hi = lo + tile; if (hi > E) hi = E;
    int cnt = hi - lo;
    for (int i = tid; i < cnt; i += 1024) atomicAdd(&S.c.lh[dst[lo + i] >> BSH], 1);
    __syncthreads();
    int h = S.c.lh[tid];
    S.c.ls[tid] = h;
    __syncthreads();
    for (int ofs = 1; ofs < 1024; ofs <<= 1) {
      int u = (tid >= ofs) ? S.c.ls[tid - ofs] : 0;
      __syncthreads();
      S.c.ls[tid] += u;
      __syncthreads();
    }
    int excl = S.c.ls[tid] - h;
    __syncthreads();
    S.c.ls[tid] = excl;
    S.c.lc[tid] = excl;
    __syncthreads();
    for (int i = tid; i < cnt; i += 1024) {
      int d = dst[lo + i];
      int b = d >> BSH;
      unsigned pk = (unsigned)src[lo + i] | ((unsigned)(d & 127) << 20);
      int p = atomicAdd(&S.c.lc[b], 1);
      S.c.sbuf[p] = pk;
      S.c.sbkt[p] = (unsigned short)b;
    }
    __syncthreads();
    for (int j = tid; j < cnt; j += 1024) {
      int b = S.c.sbkt[j];
      tmp[S.c.gb2[b] + (j - S.c.ls[b])] = S.c.sbuf[j];
    }
  }
  gg.sync();

  // ---- phase D: per-bucket counting sort -> rowptr/dinv/col ----
  for (int bk = t; bk < NB; bk += NBLK) {
    int n0 = bk << BSH;
    int part = 0;
    for (int j = tid; j < bk; j += 1024) part += btot[j];
    S.d.red[tid] = part;
    __syncthreads();
    for (int ofs = 512; ofs > 0; ofs >>= 1) {
      if (tid < ofs) S.d.red[tid] += S.d.red[tid + ofs];
      __syncthreads();
    }
    int base = S.d.red[0];
    int cnt = btot[bk];
    if (tid < 128) S.d.hist[tid] = 0;
    __syncthreads();
    for (int i = tid; i < cnt; i += 1024) atomicAdd(&S.d.hist[(tmp[base + i] >> 20) & 127], 1);
    __syncthreads();
    if (tid < 128) S.d.sc[tid] = S.d.hist[tid];
    __syncthreads();
    for (int ofs = 1; ofs < 128; ofs <<= 1) {
      int v = (tid < 128 && tid >= ofs) ? S.d.sc[tid - ofs] : 0;
      __syncthreads();
      if (tid < 128) S.d.sc[tid] += v;
      __syncthreads();
    }
    if (tid < 128) {
      int excl = S.d.sc[tid] - S.d.hist[tid];
      S.d.lcur[tid] = excl;
      int node = n0 + tid;
      if (node < N) {
        rowptr[node] = base + excl;
        dinv[node] = rsqrtf((float)S.d.hist[tid] + 1.0f);
      }
    }
    if (bk == 0 && tid == 0) rowptr[N] = E;
    __syncthreads();
    if (cnt <= BCAP) {
      for (int i = tid; i < cnt; i += 1024) {
        unsigned pk = tmp[base + i];
        int p = atomicAdd(&S.d.lcur[(pk >> 20) & 127], 1);
        S.d.buf[p] = pk & 0xFFFFFu;
      }
      __syncthreads();
      for (int i = tid; i < cnt; i += 1024) col[base + i] = (int)S.d.buf[i];
      __syncthreads();
    } else {
      for (int i = tid; i < cnt; i += 1024) {
        unsigned pk = tmp[base + i];
        int p = atomicAdd(&S.d.lcur[(pk >> 20) & 127], 1);
        col[base + p] = (int)(pk & 0xFFFFFu);
      }
      __syncthreads();
    }
  }
}

// ---------- MFMA GEMM: [M x 128] @ [128 x 128], bf16 MFMA, fp32 acc ----------
// Epilogue scales row r by dscale[r] (fold dinv into the table so the agg
// gather needs no per-neighbor weight), bf16 out.
#define WSTRIDE 136
template <int BF16IN>
__global__ __launch_bounds__(256) void k_gemm(const void* __restrict__ Ap,
    const bf16_t* __restrict__ Wtg, const float* __restrict__ dscale,
    bf16_t* __restrict__ Co, int M) {
  __shared__ bf16_t Wt[128 * WSTRIDE];
  int tid = threadIdx.x;
  for (int c2 = tid; c2 < 2048; c2 += 256) {   // 2048 x 8-bf16 chunks
    int n = c2 >> 4;
    int k8 = (c2 & 15) << 3;
    *(uint4*)&Wt[n * WSTRIDE + k8] = *(const uint4*)&Wtg[n * 128 + k8];
  }
  __syncthreads();

  int wave = tid >> 6;
  int lane = tid & 63;
  int m = lane & 15;
  int q = lane >> 4;
  int nstrips = (M + 63) >> 6;

  for (int s = blockIdx.x; s < nstrips; s += gridDim.x) {
    int rowA = s * 64 + wave * 16 + m;
    if (rowA > M - 1) rowA = M - 1;
    bf16x8 a[4];
#pragma unroll
    for (int c = 0; c < 4; c++) {
      if (BF16IN) {
        a[c] = *(const bf16x8*)((const bf16_t*)Ap + (size_t)rowA * CDIM + c * 32 + q * 8);
      } else {
        const float* ap = (const float*)Ap + (size_t)rowA * CDIM + c * 32 + q * 8;
        float4 f0 = *(const float4*)ap;
        float4 f1 = *(const float4*)(ap + 4);
        union { bf16x8 v; unsigned short u[8]; } ua;
        ua.u[0] = f2bf(f0.x); ua.u[1] = f2bf(f0.y); ua.u[2] = f2bf(f0.z); ua.u[3] = f2bf(f0.w);
        ua.u[4] = f2bf(f1.x); ua.u[5] = f2bf(f1.y); ua.u[6] = f2bf(f1.z); ua.u[7] = f2bf(f1.w);
        a[c] = ua.v;
      }
    }
    float sc[4];
#pragma unroll
    for (int r = 0; r < 4; r++) {
      int row = s * 64 + wave * 16 + q * 4 + r;
      sc[r] = (row < M) ? dscale[row] : 0.f;
    }
#pragma unroll
    for (int t = 0; t < 8; t++) {
      f32x4 acc = {0.f, 0.f, 0.f, 0.f};
#pragma unroll
      for (int c = 0; c < 4; c++) {
        bf16x8 bv = *(const bf16x8*)&Wt[(t * 16 + m) * WSTRIDE + c * 32 + q * 8];
        acc = __builtin_amdgcn_mfma_f32_16x16x32_bf16(a[c], bv, acc, 0, 0, 0);
      }
#pragma unroll
      for (int r = 0; r < 4; r++) {
        int row = s * 64 + wave * 16 + q * 4 + r;
        if (row < M) Co[(size_t)row * CDIM + t * 16 + m] = f2bf(acc[r] * sc[r]);
      }
    }
  }
}

// ---- gather batch pipeline: table rows are pre-scaled by dinv[s], so an
// edge contributes a pure ADD of its row. Fake lanes use the zero row at
// index N -> unmasked fast path. Per 8 edges: 8 readlane + 8 row loads + 16 adds.
#define GISS(S, V, JJ) \
  { _Pragma("unroll") for (int u = 0; u < 8; u++) \
      S[u] = __builtin_amdgcn_readlane(sL, (JJ) + u); \
    _Pragma("unroll") for (int u = 0; u < 8; u++) \
      V[u] = tp[(size_t)S[u] * 64 + lane]; }
#define GCON(V) \
  { _Pragma("unroll") for (int u = 0; u < 8; u++) { \
      a0 += bflo(V[u]); a1 += bfhi(V[u]); } }
#define GBLOCK(CNT) \
  { int nb = ((CNT) + 7) >> 3; \
    GISS(sA, vA, 0); \
    int b_ = 1; \
    for (; b_ + 1 < nb; b_ += 2) { \
      GISS(sB, vB, b_ * 8);       GCON(vA); \
      GISS(sA, vA, (b_ + 1) * 8); GCON(vB); \
    } \
    if (b_ < nb) { GISS(sB, vB, b_ * 8); GCON(vA); GCON(vB); } \
    else { GCON(vA); } }

// ---------- fused layer-1 aggregation + layer-2 GEMM --------------------------
// Block = 1024 thr / 64 nodes. Phase 1: each wave gathers 4 nodes, h rows ->
// LDS. Phase 2: 16 waves MFMA the 64x128 h-tile; B-fragments read directly
// from GLOBAL (W2 is L1/L2-resident; MFMA phase runs once per block) -> LDS
// drops 52.2 -> 17.4 KB, removing the 2-blocks/CU wave-occupancy conflict.
__global__ __launch_bounds__(1024) void k_aggg(const bf16_t* __restrict__ t,
    const int* __restrict__ rowptr, const int* __restrict__ col,
    const float* __restrict__ dinv, const float* __restrict__ bias,
    const bf16_t* __restrict__ Wtg, bf16_t* __restrict__ to, int N) {
  __shared__ unsigned hs[64 * 68];
  int tid = threadIdx.x;
  int wave = tid >> 6, lane = tid & 63;
  const unsigned* tp = (const unsigned*)t;
  float2 bb = ((const float2*)bias)[lane];
  int sA[8]; unsigned vA[8];
  int sB[8]; unsigned vB[8];
  int nbase = blockIdx.x * 64;
#pragma unroll 1
  for (int i = 0; i < 4; i++) {
    int node = nbase + wave * 4 + i;
    unsigned hv = 0u;
    if (node < N) {
      float di = dinv[node];
      unsigned sv = tp[(size_t)node * 64 + lane];
      float a0 = bflo(sv), a1 = bfhi(sv);
      int beg = rowptr[node], end = rowptr[node + 1];
      for (int base = beg; base < end; base += 64) {
        int cnt = end - base; if (cnt > 64) cnt = 64;
        int sL = N;
        if (lane < cnt) sL = col[base + lane];
        GBLOCK(cnt);
      }
      float o0 = fmaxf(fmaf(di, a0, bb.x), 0.f);
      float o1 = fmaxf(fmaf(di, a1, bb.y), 0.f);
      hv = ((unsigned)f2bf(o1) << 16) | f2bf(o0);
    }
    hs[(wave * 4 + i) * 68 + lane] = hv;
  }
  __syncthreads();
  // MFMA phase: wave -> rows (wave&3)*16..+15, cols t in {(wave>>2)*2, +1}
  int rg = wave & 3, cg = wave >> 2;
  int m = lane & 15, q = lane >> 4;
  bf16x8 a[4];
#pragma unroll
  for (int c = 0; c < 4; c++)
    a[c] = *(const bf16x8*)&hs[(rg * 16 + m) * 68 + c * 16 + q * 4];
  float sc4[4]; int rows[4];
#pragma unroll
  for (int r = 0; r < 4; r++) {
    int row = nbase + rg * 16 + q * 4 + r;
    rows[r] = row;
    sc4[r] = (row < N) ? dinv[row] : 0.f;
  }
#pragma unroll
  for (int tt = 0; tt < 2; tt++) {
    int tcol = cg * 2 + tt;
    f32x4 acc = {0.f, 0.f, 0.f, 0.f};
#pragma unroll
    for (int c = 0; c < 4; c++) {
      bf16x8 bv = *(const bf16x8*)&Wtg[(tcol * 16 + m) * 128 + c * 32 + q * 8];
      acc = __builtin_amdgcn_mfma_f32_16x16x32_bf16(a[c], bv, acc, 0, 0, 0);
    }
#pragma unroll
    for (int r = 0; r < 4; r++)
      if (rows[r] < N)
        to[(size_t)rows[r] * CDIM + tcol * 16 + m] = f2bf(acc[r] * sc4[r]);
  }
}

// ---------- layer-2 gather aggregation fused with mean-pool -------------------
// 16 consecutive nodes per wave (R4-proven shape).
__global__ __launch_bounds__(256) void k_aggp(const bf16_t* __restrict__ t,
    const int* __restrict__ rowptr, const int* __restrict__ col,
    const float* __restrict__ dinv, const float* __restrict__ bias,
    const int* __restrict__ batch, float* __restrict__ gsum, int N) {
  int wave = threadIdx.x >> 6;
  int lane = threadIdx.x & 63;
  int n0 = (blockIdx.x * 4 + wave) * 16;
  if (n0 >= N) return;
  int nEnd = n0 + 16; if (nEnd > N) nEnd = N;
  const unsigned* tp = (const unsigned*)t;
  float2 bb = ((const float2*)bias)[lane];
  float p0 = 0.f, p1 = 0.f;
  int curb = batch[n0];
  int sA[8]; unsigned vA[8];
  int sB[8]; unsigned vB[8];

  for (int node = n0; node < nEnd; node++) {
    float di = dinv[node];
    unsigned sv = tp[(size_t)node * 64 + lane];
    float a0 = bflo(sv);
    float a1 = bfhi(sv);
    int beg = rowptr[node], end = rowptr[node + 1];
    for (int base = beg; base < end; base += 64) {
      int cnt = end - base; if (cnt > 64) cnt = 64;
      int sL = N;
      if (lane < cnt) sL = col[base + lane];
      GBLOCK(cnt);
    }
    float o0 = fmaxf(fmaf(di, a0, bb.x), 0.f);
    float o1 = fmaxf(fmaf(di, a1, bb.y), 0.f);
    int b = batch[node];
    if (b != curb) {
      atomicAdd(&gsum[curb * CDIM + 2 * lane], p0);
      atomicAdd(&gsum[curb * CDIM + 2 * lane + 1], p1);
      curb = b; p0 = p1 = 0.f;
    }
    // keep bf16 rounding of h before pooling (parity with previous absmax)
    p0 += __uint_as_float((unsigned)f2bf(o0) << 16);
    p1 += __uint_as_float((unsigned)f2bf(o1) << 16);
  }
  atomicAdd(&gsum[curb * CDIM + 2 * lane], p0);
  atomicAdd(&gsum[curb * CDIM + 2 * lane + 1], p1);
}

// ---------- fused MLP head: pool-divide + mlp1 + mlp2 + mlp3 ------------------
__global__ __launch_bounds__(512) void k_mlp(const float* __restrict__ g,
    const int* __restrict__ batch, int N,
    const float* __restrict__ Wm1, const float* __restrict__ bm1,
    const float* __restrict__ Wm2, const float* __restrict__ bm2,
    const float* __restrict__ wm3, const float* __restrict__ bm3,
    float* __restrict__ out) {
  __shared__ float gs[CDIM];
  __shared__ float m1s[500];
  __shared__ float m2s[100];
  int bi = blockIdx.x, tid = threadIdx.x;
  if (tid < CDIM) {
    int lo = 0, hi = N;
    while (lo < hi) { int mid = (lo + hi) >> 1; if (batch[mid] < bi) lo = mid + 1; else hi = mid; }
    int s = lo;
    lo = 0; hi = N;
    int key = bi + 1;
    while (lo < hi) { int mid = (lo + hi) >> 1; if (batch[mid] < key) lo = mid + 1; else hi = mid; }
    float inv = 1.f / fmaxf((float)(lo - s), 1.f);
    gs[tid] = g[bi * CDIM + tid] * inv;
  }
  __syncthreads();
  if (tid < 500) {
    float acc = bm1[tid];
#pragma unroll 4
    for (int k = 0; k < CDIM; k++) acc = fmaf(gs[k], Wm1[k * 500 + tid], acc);
    m1s[tid] = fmaxf(acc, 0.f);
  }
  __syncthreads();
  if (tid < 100) {
    float acc = bm2[tid];
    for (int k = 0; k < 500; k++) acc = fmaf(m1s[k], Wm2[k * 100 + tid], acc);
    m2s[tid] = fmaxf(acc, 0.f) * wm3[tid];
  }
  __syncthreads();
  if (tid < 64) {
    float v = m2s[tid] + ((tid + 64 < 100) ? m2s[tid + 64] : 0.f);
#pragma unroll
    for (int ofs = 32; ofs > 0; ofs >>= 1) v += __shfl_down(v, ofs, 64);
    if (tid == 0) out[bi] = v + bm3[0];
  }
}

static inline size_t align_up(size_t v) { return (v + 255) & ~(size_t)255; }

extern "C" void kernel_launch(void* const* d_in, const int* in_sizes, int n_in,
                              void* d_out, int out_size, void* d_ws, size_t ws_size,
                              hipStream_t stream) {
  const float* x   = (const float*)d_in[0];
  const int*   ei  = (const int*)d_in[1];
  const int*   bat = (const int*)d_in[2];
  const float* W1  = (const float*)d_in[3];
  const float* b1  = (const float*)d_in[4];
  const float* W2  = (const float*)d_in[5];
  const float* b2  = (const float*)d_in[6];
  const float* Wm1 = (const float*)d_in[7];
  const float* bm1 = (const float*)d_in[8];
  const float* Wm2 = (const float*)d_in[9];
  const float* bm2 = (const float*)d_in[10];
  const float* Wm3 = (const float*)d_in[11];
  const float* bm3 = (const float*)d_in[12];
  float* out = (float*)d_out;

  const int E = in_sizes[1] / 2;
  const int N = in_sizes[2];
  const int* src = ei;
  const int* dst = ei + E;
  const int NB = (N + 127) >> BSH;
  const int M  = NB * NBLK;              // phist elements

  char* p = (char*)d_ws;
  bf16_t* t    = (bf16_t*)p;   p += align_up((size_t)(N + 1) * CDIM * 2);  // t1 (+zero row)
  bf16_t* t2   = (bf16_t*)p;   p += align_up((size_t)(N + 1) * CDIM * 2);  // t2 (+zero row)
  int* rowptr  = (int*)p;      p += align_up((size_t)(N + 1) * 4);
  int* colx    = (int*)p;      p += align_up((size_t)E * 4);
  unsigned* tmp= (unsigned*)p; p += align_up((size_t)E * 4);
  float* dinv  = (float*)p;    p += align_up((size_t)N * 4);
  int* phist   = (int*)p;      p += align_up((size_t)M * 4);
  int* btot    = (int*)p;      p += align_up((size_t)NB * 4);
  bf16_t* Wtg1 = (bf16_t*)p;   p += align_up((size_t)CDIM * CDIM * 2);
  bf16_t* Wtg2 = (bf16_t*)p;   p += align_up((size_t)CDIM * CDIM * 2);
  float* gb    = (float*)p;    p += align_up((size_t)NGRAPH * CDIM * 4);
  (void)ws_size; (void)n_in; (void)out_size;

  int Nv = N, Ev = E, NBv = NB;
  void* sargs[] = {
    (void*)&src, (void*)&dst, (void*)&phist, (void*)&btot, (void*)&tmp,
    (void*)&W1, (void*)&W2, (void*)&Wtg1, (void*)&Wtg2, (void*)&gb,
    (void*)&t, (void*)&t2, (void*)&rowptr, (void*)&dinv, (void*)&colx,
    (void*)&Nv, (void*)&Ev, (void*)&NBv };
  hipLaunchCooperativeKernel((const void*)k_sort, dim3(NBLK), dim3(1024),
                             sargs, 0, stream);

  k_gemm<0><<<1024, 256, 0, stream>>>(x, Wtg1, dinv, t, N);
  k_aggg<<<(N + 63) / 64, 1024, 0, stream>>>(t, rowptr, colx, dinv, b1, Wtg2, t2, N);
  int pwaves = (N + 15) / 16;
  k_aggp<<<(pwaves + 3) / 4, 256, 0, stream>>>(t2, rowptr, colx, dinv, b2, bat, gb, N);
  k_mlp<<<NGRAPH, 512, 0, stream>>>(gb, bat, N, Wm1, bm1, Wm2, bm2, Wm3, bm3, out);
}

// Round 8
// 356.194 us; speedup vs baseline: 1.3282x; 1.3282x over previous
//
#include <hip/hip_runtime.h>

#define CDIM 128
#define NGRAPH 256
#define BSH 7                 // 128 nodes per bucket
#define BCAP 4096             // LDS sort capacity (mean 2048, +45 sigma)
#define NBLK 256              // blocks for two-pass scatter
#define TILE 6272             // >= ceil(E/NBLK) = 6250

typedef unsigned short bf16_t;
typedef __attribute__((ext_vector_type(8))) short bf16x8;  // MFMA A/B frag (4 VGPRs)
typedef __attribute__((ext_vector_type(4))) float f32x4;   // MFMA C/D frag

__device__ __forceinline__ float bflo(unsigned u) { return __uint_as_float(u << 16); }
__device__ __forceinline__ float bfhi(unsigned u) { return __uint_as_float(u & 0xffff0000u); }
__device__ __forceinline__ unsigned short f2bf(float f) {
  unsigned u = __float_as_uint(f);
  u += 0x7fffu + ((u >> 16) & 1u);   // round-to-nearest-even
  return (unsigned short)(u >> 16);
}

// pass A + prologue: W transpose->bf16, gb zero-init, zero pad rows of t1/t2,
// per-block bucket histogram.
__global__ __launch_bounds__(1024) void k_phist(const int* __restrict__ dst,
    int* __restrict__ phist, const float* __restrict__ W1,
    const float* __restrict__ W2, bf16_t* __restrict__ Wtg1,
    bf16_t* __restrict__ Wtg2, float* __restrict__ gb, bf16_t* __restrict__ tz1,
    bf16_t* __restrict__ tz2, int N, int E, int NB) {
  __shared__ int hist[1024];
  int t = blockIdx.x, tid = threadIdx.x;
  int gidx = t * 1024 + tid;
  if (gidx < 16384) {                       // W prep (blocks 0..15)
    int n = gidx >> 7, k = gidx & 127;
    Wtg1[n * 128 + k] = f2bf(W1[k * 128 + n]);
    Wtg2[n * 128 + k] = f2bf(W2[k * 128 + n]);
  }
  if (gidx < NGRAPH * CDIM) gb[gidx] = 0.f; // gb zero (blocks 0..31)
  if (gidx < 64) {                          // zero pad row N (fake-edge target)
    ((unsigned*)(tz1 + (size_t)N * CDIM))[gidx] = 0u;
    ((unsigned*)(tz2 + (size_t)N * CDIM))[gidx] = 0u;
  }
  for (int i = tid; i < NB; i += 1024) hist[i] = 0;
  __syncthreads();
  int tile = (E + NBLK - 1) / NBLK;
  int lo = t * tile;
  int hi = lo + tile; if (hi > E) hi = E;
  for (int i = lo + tid; i < hi; i += 1024) atomicAdd(&hist[dst[i] >> BSH], 1);
  __syncthreads();
  for (int i = tid; i < NB; i += 1024) phist[i * NBLK + t] = hist[i];
}

// per-bucket scan: block b scans phist[b*NBLK .. +256] -> pexc (exclusive),
// keeps phist intact (pscatter reuses it as its local histogram), total -> btot.
__global__ __launch_bounds__(256) void k_bscan(const int* __restrict__ phist,
    int* __restrict__ pexc, int* __restrict__ btot) {
  __shared__ int wsum[4];
  int b = blockIdx.x;
  int tid = threadIdx.x, lane = tid & 63, wave = tid >> 6;
  int orig = phist[b * NBLK + tid];
  int v = orig;
#pragma unroll
  for (int ofs = 1; ofs < 64; ofs <<= 1) {
    int u = __shfl_up(v, ofs, 64);
    if (lane >= ofs) v += u;
  }
  if (lane == 63) wsum[wave] = v;
  __syncthreads();
  int add = 0;
#pragma unroll
  for (int w = 0; w < 3; w++) if (w < wave) add += wsum[w];
  int incl = v + add;
  pexc[b * NBLK + tid] = incl - orig;    // within-bucket exclusive offset
  if (tid == 255) btot[b] = incl;
}

// pass B: LDS local counting sort by bucket, then run-coalesced write-out to
// each bucket's pre-reserved disjoint region. Local histogram comes straight
// from the phist column (no dst re-read / LDS atomic hist pass).
__global__ __launch_bounds__(1024) void k_pscatter(const int* __restrict__ src,
    const int* __restrict__ dst, const int* __restrict__ phist,
    const int* __restrict__ pexc, const int* __restrict__ btot,
    unsigned* __restrict__ tmp, int E, int NB) {
  __shared__ int ls[1024];            // scans (reused)
  __shared__ int lc[1024];            // cursors
  __shared__ int gb2[1024];           // global dest base per bucket for this block
  __shared__ unsigned short sbkt[TILE];
  __shared__ unsigned sbuf[TILE];
  int t = blockIdx.x, tid = threadIdx.x;

  // global bucket base = exclusive-scan(btot)[b] + this block's in-bucket offset
  int v = (tid < NB) ? btot[tid] : 0;
  ls[tid] = v;
  __syncthreads();
  for (int ofs = 1; ofs < 1024; ofs <<= 1) {
    int u = (tid >= ofs) ? ls[tid - ofs] : 0;
    __syncthreads();
    ls[tid] += u;
    __syncthreads();
  }
  int h = (tid < NB) ? phist[tid * NBLK + t] : 0;   // this block's bucket counts
  if (tid < NB) gb2[tid] = (ls[tid] - v) + pexc[tid * NBLK + t];
  __syncthreads();
  // local exclusive scan of h over buckets
  ls[tid] = h;
  __syncthreads();
  for (int ofs = 1; ofs < 1024; ofs <<= 1) {
    int u = (tid >= ofs) ? ls[tid - ofs] : 0;
    __syncthreads();
    ls[tid] += u;
    __syncthreads();
  }
  int excl = ls[tid] - h;
  __syncthreads();
  ls[tid] = excl;
  lc[tid] = excl;
  __syncthreads();

  int tile = (E + NBLK - 1) / NBLK;
  int lo = t * tile;
  int hi = lo + tile; if (hi > E) hi = E;
  int cnt = hi - lo;

  // local sort into sbuf/sbkt
  for (int i = tid; i < cnt; i += 1024) {
    int d = dst[lo + i];
    int b = d >> BSH;
    unsigned pk = (unsigned)src[lo + i] | ((unsigned)(d & 127) << 20);
    int p = atomicAdd(&lc[b], 1);
    sbuf[p] = pk;
    sbkt[p] = (unsigned short)b;
  }
  __syncthreads();

  // coalesced run write-out
  for (int j = tid; j < cnt; j += 1024) {
    int b = sbkt[j];
    tmp[gb2[b] + (j - ls[b])] = sbuf[j];
  }
}

// pass C: per-bucket LDS histogram + scan + counting sort; emits rowptr/dinv/col.
__global__ __launch_bounds__(256) void k_csort2(const unsigned* __restrict__ tmp,
    const int* __restrict__ btot, int* __restrict__ rowptr, float* __restrict__ dinv,
    int* __restrict__ col, int N, int NB, int E) {
  __shared__ int hist[128];
  __shared__ int sc[128];
  __shared__ int lcur[128];
  __shared__ int red[256];
  __shared__ unsigned buf[BCAP];
  int b = blockIdx.x;
  int n0 = b << BSH;
  int tid = threadIdx.x;
  int part = 0;
  for (int j = tid; j < b; j += 256) part += btot[j];
  red[tid] = part;
  __syncthreads();
  for (int ofs = 128; ofs > 0; ofs >>= 1) {
    if (tid < ofs) red[tid] += red[tid + ofs];
    __syncthreads();
  }
  int base = red[0];
  int cnt = btot[b];
  if (tid < 128) hist[tid] = 0;
  __syncthreads();
  for (int i = tid; i < cnt; i += 256) atomicAdd(&hist[(tmp[base + i] >> 20) & 127], 1);
  __syncthreads();
  if (tid < 128) sc[tid] = hist[tid];
  __syncthreads();
  for (int ofs = 1; ofs < 128; ofs <<= 1) {
    int v = (tid < 128 && tid >= ofs) ? sc[tid - ofs] : 0;
    __syncthreads();
    if (tid < 128) sc[tid] += v;
    __syncthreads();
  }
  if (tid < 128) {
    int excl = sc[tid] - hist[tid];
    lcur[tid] = excl;
    int node = n0 + tid;
    if (node < N) {
      rowptr[node] = base + excl;
      dinv[node] = rsqrtf((float)hist[tid] + 1.0f);
    }
  }
  if (b == 0 && tid == 0) rowptr[N] = E;
  __syncthreads();
  if (cnt <= BCAP) {
    for (int i = tid; i < cnt; i += 256) {
      unsigned pk = tmp[base + i];
      int p = atomicAdd(&lcur[(pk >> 20) & 127], 1);
      buf[p] = pk & 0xFFFFFu;
    }
    __syncthreads();
    for (int i = tid; i < cnt; i += 256) col[base + i] = (int)buf[i];
  } else {
    for (int i = tid; i < cnt; i += 256) {
      unsigned pk = tmp[base + i];
      int p = atomicAdd(&lcur[(pk >> 20) & 127], 1);
      col[base + p] = (int)(pk & 0xFFFFFu);
    }
  }
}

// ---------- MFMA GEMM: [M x 128] @ [128 x 128], bf16 MFMA, fp32 acc ----------
// Epilogue scales row r by dscale[r] (fold dinv into the table so the agg
// gather needs no per-neighbor weight), bf16 out.
#define WSTRIDE 136
template <int BF16IN>
__global__ __launch_bounds__(256) void k_gemm(const void* __restrict__ Ap,
    const bf16_t* __restrict__ Wtg, const float* __restrict__ dscale,
    bf16_t* __restrict__ Co, int M) {
  __shared__ bf16_t Wt[128 * WSTRIDE];
  int tid = threadIdx.x;
  for (int c2 = tid; c2 < 2048; c2 += 256) {   // 2048 x 8-bf16 chunks
    int n = c2 >> 4;
    int k8 = (c2 & 15) << 3;
    *(uint4*)&Wt[n * WSTRIDE + k8] = *(const uint4*)&Wtg[n * 128 + k8];
  }
  __syncthreads();

  int wave = tid >> 6;
  int lane = tid & 63;
  int m = lane & 15;
  int q = lane >> 4;
  int nstrips = (M + 63) >> 6;

  for (int s = blockIdx.x; s < nstrips; s += gridDim.x) {
    int rowA = s * 64 + wave * 16 + m;
    if (rowA > M - 1) rowA = M - 1;
    bf16x8 a[4];
#pragma unroll
    for (int c = 0; c < 4; c++) {
      if (BF16IN) {
        a[c] = *(const bf16x8*)((const bf16_t*)Ap + (size_t)rowA * CDIM + c * 32 + q * 8);
      } else {
        const float* ap = (const float*)Ap + (size_t)rowA * CDIM + c * 32 + q * 8;
        float4 f0 = *(const float4*)ap;
        float4 f1 = *(const float4*)(ap + 4);
        union { bf16x8 v; unsigned short u[8]; } ua;
        ua.u[0] = f2bf(f0.x); ua.u[1] = f2bf(f0.y); ua.u[2] = f2bf(f0.z); ua.u[3] = f2bf(f0.w);
        ua.u[4] = f2bf(f1.x); ua.u[5] = f2bf(f1.y); ua.u[6] = f2bf(f1.z); ua.u[7] = f2bf(f1.w);
        a[c] = ua.v;
      }
    }
    float sc[4];
#pragma unroll
    for (int r = 0; r < 4; r++) {
      int row = s * 64 + wave * 16 + q * 4 + r;
      sc[r] = (row < M) ? dscale[row] : 0.f;
    }
#pragma unroll
    for (int t = 0; t < 8; t++) {
      f32x4 acc = {0.f, 0.f, 0.f, 0.f};
#pragma unroll
      for (int c = 0; c < 4; c++) {
        bf16x8 bv = *(const bf16x8*)&Wt[(t * 16 + m) * WSTRIDE + c * 32 + q * 8];
        acc = __builtin_amdgcn_mfma_f32_16x16x32_bf16(a[c], bv, acc, 0, 0, 0);
      }
#pragma unroll
      for (int r = 0; r < 4; r++) {
        int row = s * 64 + wave * 16 + q * 4 + r;
        if (row < M) Co[(size_t)row * CDIM + t * 16 + m] = f2bf(acc[r] * sc[r]);
      }
    }
  }
}

// ---- gather batch pipeline: table rows are pre-scaled by dinv[s], so an
// edge contributes a pure ADD of its row. Fake lanes use the zero row at
// index N -> unmasked fast path. Per 8 edges: 8 readlane + 8 row loads + 16 adds.
#define GISS(S, V, JJ) \
  { _Pragma("unroll") for (int u = 0; u < 8; u++) \
      S[u] = __builtin_amdgcn_readlane(sL, (JJ) + u); \
    _Pragma("unroll") for (int u = 0; u < 8; u++) \
      V[u] = tp[(size_t)S[u] * 64 + lane]; }
#define GCON(V) \
  { _Pragma("unroll") for (int u = 0; u < 8; u++) { \
      a0 += bflo(V[u]); a1 += bfhi(V[u]); } }
#define GBLOCK(CNT) \
  { int nb = ((CNT) + 7) >> 3; \
    GISS(sA, vA, 0); \
    int b_ = 1; \
    for (; b_ + 1 < nb; b_ += 2) { \
      GISS(sB, vB, b_ * 8);       GCON(vA); \
      GISS(sA, vA, (b_ + 1) * 8); GCON(vB); \
    } \
    if (b_ < nb) { GISS(sB, vB, b_ * 8); GCON(vA); GCON(vB); } \
    else { GCON(vA); } }

// ---------- fused layer-1 aggregation + layer-2 GEMM --------------------------
// Block = 1024 thr / 64 nodes. Phase 1: each wave gathers 4 nodes, h rows ->
// LDS. Phase 2: 16 waves MFMA the 64x128 h-tile; B-fragments read directly
// from GLOBAL (W2 is L1/L2-resident; MFMA phase runs once per block) -> LDS
// drops 52.2 -> 17.4 KB so 2 blocks/CU interleave gather and MFMA phases.
__global__ __launch_bounds__(1024) void k_aggg(const bf16_t* __restrict__ t,
    const int* __restrict__ rowptr, const int* __restrict__ col,
    const float* __restrict__ dinv, const float* __restrict__ bias,
    const bf16_t* __restrict__ Wtg, bf16_t* __restrict__ to, int N) {
  __shared__ unsigned hs[64 * 68];
  int tid = threadIdx.x;
  int wave = tid >> 6, lane = tid & 63;
  const unsigned* tp = (const unsigned*)t;
  float2 bb = ((const float2*)bias)[lane];
  int sA[8]; unsigned vA[8];
  int sB[8]; unsigned vB[8];
  int nbase = blockIdx.x * 64;
#pragma unroll 1
  for (int i = 0; i < 4; i++) {
    int node = nbase + wave * 4 + i;
    unsigned hv = 0u;
    if (node < N) {
      float di = dinv[node];
      unsigned sv = tp[(size_t)node * 64 + lane];
      float a0 = bflo(sv), a1 = bfhi(sv);
      int beg = rowptr[node], end = rowptr[node + 1];
      for (int base = beg; base < end; base += 64) {
        int cnt = end - base; if (cnt > 64) cnt = 64;
        int sL = N;
        if (lane < cnt) sL = col[base + lane];
        GBLOCK(cnt);
      }
      float o0 = fmaxf(fmaf(di, a0, bb.x), 0.f);
      float o1 = fmaxf(fmaf(di, a1, bb.y), 0.f);
      hv = ((unsigned)f2bf(o1) << 16) | f2bf(o0);
    }
    hs[(wave * 4 + i) * 68 + lane] = hv;
  }
  __syncthreads();
  // MFMA phase: wave -> rows (wave&3)*16..+15, cols t in {(wave>>2)*2, +1}
  int rg = wave & 3, cg = wave >> 2;
  int m = lane & 15, q = lane >> 4;
  bf16x8 a[4];
#pragma unroll
  for (int c = 0; c < 4; c++)
    a[c] = *(const bf16x8*)&hs[(rg * 16 + m) * 68 + c * 16 + q * 4];
  float sc4[4]; int rows[4];
#pragma unroll
  for (int r = 0; r < 4; r++) {
    int row = nbase + rg * 16 + q * 4 + r;
    rows[r] = row;
    sc4[r] = (row < N) ? dinv[row] : 0.f;
  }
#pragma unroll
  for (int tt = 0; tt < 2; tt++) {
    int tcol = cg * 2 + tt;
    f32x4 acc = {0.f, 0.f, 0.f, 0.f};
#pragma unroll
    for (int c = 0; c < 4; c++) {
      bf16x8 bv = *(const bf16x8*)&Wtg[(tcol * 16 + m) * 128 + c * 32 + q * 8];
      acc = __builtin_amdgcn_mfma_f32_16x16x32_bf16(a[c], bv, acc, 0, 0, 0);
    }
#pragma unroll
    for (int r = 0; r < 4; r++)
      if (rows[r] < N)
        to[(size_t)rows[r] * CDIM + tcol * 16 + m] = f2bf(acc[r] * sc4[r]);
  }
}

// ---------- layer-2 gather aggregation fused with mean-pool -------------------
// 16 consecutive nodes per wave (R4-proven shape).
__global__ __launch_bounds__(256) void k_aggp(const bf16_t* __restrict__ t,
    const int* __restrict__ rowptr, const int* __restrict__ col,
    const float* __restrict__ dinv, const float* __restrict__ bias,
    const int* __restrict__ batch, float* __restrict__ gsum, int N) {
  int wave = threadIdx.x >> 6;
  int lane = threadIdx.x & 63;
  int n0 = (blockIdx.x * 4 + wave) * 16;
  if (n0 >= N) return;
  int nEnd = n0 + 16; if (nEnd > N) nEnd = N;
  const unsigned* tp = (const unsigned*)t;
  float2 bb = ((const float2*)bias)[lane];
  float p0 = 0.f, p1 = 0.f;
  int curb = batch[n0];
  int sA[8]; unsigned vA[8];
  int sB[8]; unsigned vB[8];

  for (int node = n0; node < nEnd; node++) {
    float di = dinv[node];
    unsigned sv = tp[(size_t)node * 64 + lane];
    float a0 = bflo(sv);
    float a1 = bfhi(sv);
    int beg = rowptr[node], end = rowptr[node + 1];
    for (int base = beg; base < end; base += 64) {
      int cnt = end - base; if (cnt > 64) cnt = 64;
      int sL = N;
      if (lane < cnt) sL = col[base + lane];
      GBLOCK(cnt);
    }
    float o0 = fmaxf(fmaf(di, a0, bb.x), 0.f);
    float o1 = fmaxf(fmaf(di, a1, bb.y), 0.f);
    int b = batch[node];
    if (b != curb) {
      atomicAdd(&gsum[curb * CDIM + 2 * lane], p0);
      atomicAdd(&gsum[curb * CDIM + 2 * lane + 1], p1);
      curb = b; p0 = p1 = 0.f;
    }
    // keep bf16 rounding of h before pooling (parity with previous absmax)
    p0 += __uint_as_float((unsigned)f2bf(o0) << 16);
    p1 += __uint_as_float((unsigned)f2bf(o1) << 16);
  }
  atomicAdd(&gsum[curb * CDIM + 2 * lane], p0);
  atomicAdd(&gsum[curb * CDIM + 2 * lane + 1], p1);
}

// ---------- fused MLP head: pool-divide + mlp1 + mlp2 + mlp3 ------------------
__global__ __launch_bounds__(512) void k_mlp(const float* __restrict__ g,
    const int* __restrict__ batch, int N,
    const float* __restrict__ Wm1, const float* __restrict__ bm1,
    const float* __restrict__ Wm2, const float* __restrict__ bm2,
    const float* __restrict__ wm3, const float* __restrict__ bm3,
    float* __restrict__ out) {
  __shared__ float gs[CDIM];
  __shared__ float m1s[500];
  __shared__ float m2s[100];
  int bi = blockIdx.x, tid = threadIdx.x;
  if (tid < CDIM) {
    int lo = 0, hi = N;
    while (lo < hi) { int mid = (lo + hi) >> 1; if (batch[mid] < bi) lo = mid + 1; else hi = mid; }
    int s = lo;
    lo = 0; hi = N;
    int key = bi + 1;
    while (lo < hi) { int mid = (lo + hi) >> 1; if (batch[mid] < key) lo = mid + 1; else hi = mid; }
    float inv = 1.f / fmaxf((float)(lo - s), 1.f);
    gs[tid] = g[bi * CDIM + tid] * inv;
  }
  __syncthreads();
  if (tid < 500) {
    float acc = bm1[tid];
#pragma unroll 4
    for (int k = 0; k < CDIM; k++) acc = fmaf(gs[k], Wm1[k * 500 + tid], acc);
    m1s[tid] = fmaxf(acc, 0.f);
  }
  __syncthreads();
  if (tid < 100) {
    float acc = bm2[tid];
    for (int k = 0; k < 500; k++) acc = fmaf(m1s[k], Wm2[k * 100 + tid], acc);
    m2s[tid] = fmaxf(acc, 0.f) * wm3[tid];
  }
  __syncthreads();
  if (tid < 64) {
    float v = m2s[tid] + ((tid + 64 < 100) ? m2s[tid + 64] : 0.f);
#pragma unroll
    for (int ofs = 32; ofs > 0; ofs >>= 1) v += __shfl_down(v, ofs, 64);
    if (tid == 0) out[bi] = v + bm3[0];
  }
}

static inline size_t align_up(size_t v) { return (v + 255) & ~(size_t)255; }

extern "C" void kernel_launch(void* const* d_in, const int* in_sizes, int n_in,
                              void* d_out, int out_size, void* d_ws, size_t ws_size,
                              hipStream_t stream) {
  const float* x   = (const float*)d_in[0];
  const int*   ei  = (const int*)d_in[1];
  const int*   bat = (const int*)d_in[2];
  const float* W1  = (const float*)d_in[3];
  const float* b1  = (const float*)d_in[4];
  const float* W2  = (const float*)d_in[5];
  const float* b2  = (const float*)d_in[6];
  const float* Wm1 = (const float*)d_in[7];
  const float* bm1 = (const float*)d_in[8];
  const float* Wm2 = (const float*)d_in[9];
  const float* bm2 = (const float*)d_in[10];
  const float* Wm3 = (const float*)d_in[11];
  const float* bm3 = (const float*)d_in[12];
  float* out = (float*)d_out;

  const int E = in_sizes[1] / 2;
  const int N = in_sizes[2];
  const int* src = ei;
  const int* dst = ei + E;
  const int NB = (N + 127) >> BSH;
  const int M  = NB * NBLK;              // phist elements

  char* p = (char*)d_ws;
  bf16_t* t    = (bf16_t*)p;   p += align_up((size_t)(N + 1) * CDIM * 2);  // t1 (+zero row)
  bf16_t* t2   = (bf16_t*)p;   p += align_up((size_t)(N + 1) * CDIM * 2);  // t2 (+zero row)
  int* rowptr  = (int*)p;      p += align_up((size_t)(N + 1) * 4);
  int* colx    = (int*)p;      p += align_up((size_t)E * 4);
  unsigned* tmp= (unsigned*)p; p += align_up((size_t)E * 4);
  float* dinv  = (float*)p;    p += align_up((size_t)N * 4);
  int* phist   = (int*)p;      p += align_up((size_t)M * 4);
  int* pexc    = (int*)p;      p += align_up((size_t)M * 4);
  int* btot    = (int*)p;      p += align_up((size_t)NB * 4);
  bf16_t* Wtg1 = (bf16_t*)p;   p += align_up((size_t)CDIM * CDIM * 2);
  bf16_t* Wtg2 = (bf16_t*)p;   p += align_up((size_t)CDIM * CDIM * 2);
  float* gb    = (float*)p;    p += align_up((size_t)NGRAPH * CDIM * 4);
  (void)ws_size; (void)n_in; (void)out_size;

  k_phist<<<NBLK, 1024, 0, stream>>>(dst, phist, W1, W2, Wtg1, Wtg2, gb, t, t2, N, E, NB);
  k_bscan<<<NB, 256, 0, stream>>>(phist, pexc, btot);
  k_pscatter<<<NBLK, 1024, 0, stream>>>(src, dst, phist, pexc, btot, tmp, E, NB);
  k_csort2<<<NB, 256, 0, stream>>>(tmp, btot, rowptr, dinv, colx, N, NB, E);

  k_gemm<0><<<1024, 256, 0, stream>>>(x, Wtg1, dinv, t, N);
  k_aggg<<<(N + 63) / 64, 1024, 0, stream>>>(t, rowptr, colx, dinv, b1, Wtg2, t2, N);
  int pwaves = (N + 15) / 16;
  k_aggp<<<(pwaves + 3) / 4, 256, 0, stream>>>(t2, rowptr, colx, dinv, b2, bat, gb, N);
  k_mlp<<<NGRAPH, 512, 0, stream>>>(gb, bat, N, Wm1, bm1, Wm2, bm2, Wm3, bm3, out);
}

// Round 9
// 323.492 us; speedup vs baseline: 1.4625x; 1.1011x over previous
//
#include <hip/hip_runtime.h>

#define CDIM 128
#define NGRAPH 256
#define BSH 7                 // 128 nodes per bucket
#define BCAP 4096             // LDS sort capacity (mean 2048, +45 sigma)
#define NBLK 256              // blocks for two-pass scatter
#define TILE 6272             // >= ceil(E/NBLK) = 6250

typedef unsigned short bf16_t;
typedef __attribute__((ext_vector_type(8))) short bf16x8;  // MFMA A/B frag (4 VGPRs)
typedef __attribute__((ext_vector_type(4))) float f32x4;   // MFMA C/D frag

__device__ __forceinline__ float bflo(unsigned u) { return __uint_as_float(u << 16); }
__device__ __forceinline__ float bfhi(unsigned u) { return __uint_as_float(u & 0xffff0000u); }
__device__ __forceinline__ unsigned short f2bf(float f) {
  unsigned u = __float_as_uint(f);
  u += 0x7fffu + ((u >> 16) & 1u);   // round-to-nearest-even
  return (unsigned short)(u >> 16);
}

// pass A + prologue: W transpose->bf16, gb zero-init, zero pad rows of t1/t2,
// per-block bucket histogram.
__global__ __launch_bounds__(1024) void k_phist(const int* __restrict__ dst,
    int* __restrict__ phist, const float* __restrict__ W1,
    const float* __restrict__ W2, bf16_t* __restrict__ Wtg1,
    bf16_t* __restrict__ Wtg2, float* __restrict__ gb, bf16_t* __restrict__ tz1,
    bf16_t* __restrict__ tz2, int N, int E, int NB) {
  __shared__ int hist[1024];
  int t = blockIdx.x, tid = threadIdx.x;
  int gidx = t * 1024 + tid;
  if (gidx < 16384) {                       // W prep (blocks 0..15)
    int n = gidx >> 7, k = gidx & 127;
    Wtg1[n * 128 + k] = f2bf(W1[k * 128 + n]);
    Wtg2[n * 128 + k] = f2bf(W2[k * 128 + n]);
  }
  if (gidx < NGRAPH * CDIM) gb[gidx] = 0.f; // gb zero (blocks 0..31)
  if (gidx < 64) {                          // zero pad row N (fake-edge target)
    ((unsigned*)(tz1 + (size_t)N * CDIM))[gidx] = 0u;
    ((unsigned*)(tz2 + (size_t)N * CDIM))[gidx] = 0u;
  }
  for (int i = tid; i < NB; i += 1024) hist[i] = 0;
  __syncthreads();
  int tile = (E + NBLK - 1) / NBLK;
  int lo = t * tile;
  int hi = lo + tile; if (hi > E) hi = E;
  for (int i = lo + tid; i < hi; i += 1024) atomicAdd(&hist[dst[i] >> BSH], 1);
  __syncthreads();
  for (int i = tid; i < NB; i += 1024) phist[i * NBLK + t] = hist[i];
}

// per-bucket scan: block b scans phist[b*NBLK .. +256] in place (exclusive),
// writes bucket total to btot[b].
__global__ __launch_bounds__(256) void k_bscan(int* __restrict__ phist,
    int* __restrict__ btot) {
  __shared__ int wsum[4];
  int b = blockIdx.x;
  int tid = threadIdx.x, lane = tid & 63, wave = tid >> 6;
  int orig = phist[b * NBLK + tid];
  int v = orig;
#pragma unroll
  for (int ofs = 1; ofs < 64; ofs <<= 1) {
    int u = __shfl_up(v, ofs, 64);
    if (lane >= ofs) v += u;
  }
  if (lane == 63) wsum[wave] = v;
  __syncthreads();
  int add = 0;
#pragma unroll
  for (int w = 0; w < 3; w++) if (w < wave) add += wsum[w];
  int incl = v + add;
  phist[b * NBLK + tid] = incl - orig;   // within-bucket exclusive offset
  if (tid == 255) btot[b] = incl;
}

// pass B: LDS local counting sort by bucket, then run-coalesced write-out to
// each bucket's pre-reserved disjoint region (bases exact from phist/btot).
// Replaces 1.6M isolated 4B global writes (one 64B line each) with avg-8-entry
// contiguous runs (~5x fewer write lines).
__global__ __launch_bounds__(1024) void k_pscatter(const int* __restrict__ src,
    const int* __restrict__ dst, const int* __restrict__ phist,
    const int* __restrict__ btot, unsigned* __restrict__ tmp, int E, int NB) {
  __shared__ int lh[1024];            // local bucket hist
  __shared__ int ls[1024];            // local exclusive scan (kept for write-out)
  __shared__ int lc[1024];            // cursors
  __shared__ int gb2[1024];           // global dest base per bucket for this block
  __shared__ unsigned short sbkt[TILE];
  __shared__ unsigned sbuf[TILE];
  int t = blockIdx.x, tid = threadIdx.x;

  // global bucket base = exclusive-scan(btot)[b] + this block's in-bucket offset
  int v = (tid < NB) ? btot[tid] : 0;
  ls[tid] = v;
  __syncthreads();
  for (int ofs = 1; ofs < 1024; ofs <<= 1) {
    int u = (tid >= ofs) ? ls[tid - ofs] : 0;
    __syncthreads();
    ls[tid] += u;
    __syncthreads();
  }
  if (tid < NB) gb2[tid] = (ls[tid] - v) + phist[tid * NBLK + t];
  lh[tid] = 0;
  __syncthreads();

  int tile = (E + NBLK - 1) / NBLK;
  int lo = t * tile;
  int hi = lo + tile; if (hi > E) hi = E;
  int cnt = hi - lo;

  // local histogram
  for (int i = tid; i < cnt; i += 1024) atomicAdd(&lh[dst[lo + i] >> BSH], 1);
  __syncthreads();
  // local exclusive scan
  int h = lh[tid];
  ls[tid] = h;
  __syncthreads();
  for (int ofs = 1; ofs < 1024; ofs <<= 1) {
    int u = (tid >= ofs) ? ls[tid - ofs] : 0;
    __syncthreads();
    ls[tid] += u;
    __syncthreads();
  }
  int excl = ls[tid] - h;
  __syncthreads();
  ls[tid] = excl;
  lc[tid] = excl;
  __syncthreads();

  // local sort into sbuf/sbkt (dst tile is L1/L2-resident from hist pass)
  for (int i = tid; i < cnt; i += 1024) {
    int d = dst[lo + i];
    int b = d >> BSH;
    unsigned pk = (unsigned)src[lo + i] | ((unsigned)(d & 127) << 20);
    int p = atomicAdd(&lc[b], 1);
    sbuf[p] = pk;
    sbkt[p] = (unsigned short)b;
  }
  __syncthreads();

  // coalesced run write-out: consecutive j within a bucket run -> consecutive
  // global addresses.
  for (int j = tid; j < cnt; j += 1024) {
    int b = sbkt[j];
    tmp[gb2[b] + (j - ls[b])] = sbuf[j];
  }
}

// pass C: per-bucket LDS histogram + scan + counting sort; emits rowptr/dinv/col.
// base recomputed locally from btot.
__global__ __launch_bounds__(256) void k_csort2(const unsigned* __restrict__ tmp,
    const int* __restrict__ btot, int* __restrict__ rowptr, float* __restrict__ dinv,
    int* __restrict__ col, int N, int NB, int E) {
  __shared__ int hist[128];
  __shared__ int sc[128];
  __shared__ int lcur[128];
  __shared__ int red[256];
  __shared__ unsigned buf[BCAP];
  int b = blockIdx.x;
  int n0 = b << BSH;
  int tid = threadIdx.x;
  int part = 0;
  for (int j = tid; j < b; j += 256) part += btot[j];
  red[tid] = part;
  __syncthreads();
  for (int ofs = 128; ofs > 0; ofs >>= 1) {
    if (tid < ofs) red[tid] += red[tid + ofs];
    __syncthreads();
  }
  int base = red[0];
  int cnt = btot[b];
  if (tid < 128) hist[tid] = 0;
  __syncthreads();
  for (int i = tid; i < cnt; i += 256) atomicAdd(&hist[(tmp[base + i] >> 20) & 127], 1);
  __syncthreads();
  if (tid < 128) sc[tid] = hist[tid];
  __syncthreads();
  for (int ofs = 1; ofs < 128; ofs <<= 1) {
    int v = (tid < 128 && tid >= ofs) ? sc[tid - ofs] : 0;
    __syncthreads();
    if (tid < 128) sc[tid] += v;
    __syncthreads();
  }
  if (tid < 128) {
    int excl = sc[tid] - hist[tid];
    lcur[tid] = excl;
    int node = n0 + tid;
    if (node < N) {
      rowptr[node] = base + excl;
      dinv[node] = rsqrtf((float)hist[tid] + 1.0f);
    }
  }
  if (b == 0 && tid == 0) rowptr[N] = E;
  __syncthreads();
  if (cnt <= BCAP) {
    for (int i = tid; i < cnt; i += 256) {
      unsigned pk = tmp[base + i];
      int p = atomicAdd(&lcur[(pk >> 20) & 127], 1);
      buf[p] = pk & 0xFFFFFu;
    }
    __syncthreads();
    for (int i = tid; i < cnt; i += 256) col[base + i] = (int)buf[i];
  } else {
    for (int i = tid; i < cnt; i += 256) {
      unsigned pk = tmp[base + i];
      int p = atomicAdd(&lcur[(pk >> 20) & 127], 1);
      col[base + p] = (int)(pk & 0xFFFFFu);
    }
  }
}

// ---------- MFMA GEMM: [M x 128] @ [128 x 128], bf16 MFMA, fp32 acc ----------
// Epilogue scales row r by dscale[r] (fold dinv into the table so the agg
// gather needs no per-neighbor weight), bf16 out.
#define WSTRIDE 136
template <int BF16IN>
__global__ __launch_bounds__(256) void k_gemm(const void* __restrict__ Ap,
    const bf16_t* __restrict__ Wtg, const float* __restrict__ dscale,
    bf16_t* __restrict__ Co, int M) {
  __shared__ bf16_t Wt[128 * WSTRIDE];
  int tid = threadIdx.x;
  for (int c2 = tid; c2 < 2048; c2 += 256) {   // 2048 x 8-bf16 chunks
    int n = c2 >> 4;
    int k8 = (c2 & 15) << 3;
    *(uint4*)&Wt[n * WSTRIDE + k8] = *(const uint4*)&Wtg[n * 128 + k8];
  }
  __syncthreads();

  int wave = tid >> 6;
  int lane = tid & 63;
  int m = lane & 15;
  int q = lane >> 4;
  int nstrips = (M + 63) >> 6;

  for (int s = blockIdx.x; s < nstrips; s += gridDim.x) {
    int rowA = s * 64 + wave * 16 + m;
    if (rowA > M - 1) rowA = M - 1;
    bf16x8 a[4];
#pragma unroll
    for (int c = 0; c < 4; c++) {
      if (BF16IN) {
        a[c] = *(const bf16x8*)((const bf16_t*)Ap + (size_t)rowA * CDIM + c * 32 + q * 8);
      } else {
        const float* ap = (const float*)Ap + (size_t)rowA * CDIM + c * 32 + q * 8;
        float4 f0 = *(const float4*)ap;
        float4 f1 = *(const float4*)(ap + 4);
        union { bf16x8 v; unsigned short u[8]; } ua;
        ua.u[0] = f2bf(f0.x); ua.u[1] = f2bf(f0.y); ua.u[2] = f2bf(f0.z); ua.u[3] = f2bf(f0.w);
        ua.u[4] = f2bf(f1.x); ua.u[5] = f2bf(f1.y); ua.u[6] = f2bf(f1.z); ua.u[7] = f2bf(f1.w);
        a[c] = ua.v;
      }
    }
    float sc[4];
#pragma unroll
    for (int r = 0; r < 4; r++) {
      int row = s * 64 + wave * 16 + q * 4 + r;
      sc[r] = (row < M) ? dscale[row] : 0.f;
    }
#pragma unroll
    for (int t = 0; t < 8; t++) {
      f32x4 acc = {0.f, 0.f, 0.f, 0.f};
#pragma unroll
      for (int c = 0; c < 4; c++) {
        bf16x8 bv = *(const bf16x8*)&Wt[(t * 16 + m) * WSTRIDE + c * 32 + q * 8];
        acc = __builtin_amdgcn_mfma_f32_16x16x32_bf16(a[c], bv, acc, 0, 0, 0);
      }
#pragma unroll
      for (int r = 0; r < 4; r++) {
        int row = s * 64 + wave * 16 + q * 4 + r;
        if (row < M) Co[(size_t)row * CDIM + t * 16 + m] = f2bf(acc[r] * sc[r]);
      }
    }
  }
}

// ---- gather batch pipeline: table rows are pre-scaled by dinv[s], so an
// edge contributes a pure ADD of its row. Fake lanes use the zero row at
// index N -> unmasked fast path. Per 8 edges: 8 readlane + 8 row loads + 16 adds.
#define GISS(S, V, JJ) \
  { _Pragma("unroll") for (int u = 0; u < 8; u++) \
      S[u] = __builtin_amdgcn_readlane(sL, (JJ) + u); \
    _Pragma("unroll") for (int u = 0; u < 8; u++) \
      V[u] = tp[(size_t)S[u] * 64 + lane]; }
#define GCON(V) \
  { _Pragma("unroll") for (int u = 0; u < 8; u++) { \
      a0 += bflo(V[u]); a1 += bfhi(V[u]); } }
#define GBLOCK(CNT) \
  { int nb = ((CNT) + 7) >> 3; \
    GISS(sA, vA, 0); \
    int b_ = 1; \
    for (; b_ + 1 < nb; b_ += 2) { \
      GISS(sB, vB, b_ * 8);       GCON(vA); \
      GISS(sA, vA, (b_ + 1) * 8); GCON(vB); \
    } \
    if (b_ < nb) { GISS(sB, vB, b_ * 8); GCON(vA); GCON(vB); } \
    else { GCON(vA); } }

// ---------- fused layer-1 aggregation + layer-2 GEMM --------------------------
// Block = 1024 thr / 64 nodes. Phase 1: each wave gathers 4 nodes (weight-free
// inner loop), h rows -> LDS. Phase 2: 16 waves MFMA the 64x128 h-tile against
// W2 (staged in LDS: R8 proved the global-read variant craters occupancy),
// scale rows by dinv, write t2.
__global__ __launch_bounds__(1024) void k_aggg(const bf16_t* __restrict__ t,
    const int* __restrict__ rowptr, const int* __restrict__ col,
    const float* __restrict__ dinv, const float* __restrict__ bias,
    const bf16_t* __restrict__ Wtg, bf16_t* __restrict__ to, int N) {
  __shared__ bf16_t Wt[128 * WSTRIDE];
  __shared__ unsigned hs[64 * 68];
  int tid = threadIdx.x;
  int wave = tid >> 6, lane = tid & 63;
  for (int c2 = tid; c2 < 2048; c2 += 1024) {
    int n = c2 >> 4, k8 = (c2 & 15) << 3;
    *(uint4*)&Wt[n * WSTRIDE + k8] = *(const uint4*)&Wtg[n * 128 + k8];
  }
  const unsigned* tp = (const unsigned*)t;
  float2 bb = ((const float2*)bias)[lane];
  int sA[8]; unsigned vA[8];
  int sB[8]; unsigned vB[8];
  int nbase = blockIdx.x * 64;
#pragma unroll 1
  for (int i = 0; i < 4; i++) {
    int node = nbase + wave * 4 + i;
    unsigned hv = 0u;
    if (node < N) {
      float di = dinv[node];
      unsigned sv = tp[(size_t)node * 64 + lane];
      float a0 = bflo(sv), a1 = bfhi(sv);
      int beg = rowptr[node], end = rowptr[node + 1];
      for (int base = beg; base < end; base += 64) {
        int cnt = end - base; if (cnt > 64) cnt = 64;
        int sL = N;
        if (lane < cnt) sL = col[base + lane];
        GBLOCK(cnt);
      }
      float o0 = fmaxf(fmaf(di, a0, bb.x), 0.f);
      float o1 = fmaxf(fmaf(di, a1, bb.y), 0.f);
      hv = ((unsigned)f2bf(o1) << 16) | f2bf(o0);
    }
    hs[(wave * 4 + i) * 68 + lane] = hv;
  }
  __syncthreads();
  // MFMA phase: wave -> rows (wave&3)*16..+15, cols t in {(wave>>2)*2, +1}
  int rg = wave & 3, cg = wave >> 2;
  int m = lane & 15, q = lane >> 4;
  bf16x8 a[4];
#pragma unroll
  for (int c = 0; c < 4; c++)
    a[c] = *(const bf16x8*)&hs[(rg * 16 + m) * 68 + c * 16 + q * 4];
  float sc4[4]; int rows[4];
#pragma unroll
  for (int r = 0; r < 4; r++) {
    int row = nbase + rg * 16 + q * 4 + r;
    rows[r] = row;
    sc4[r] = (row < N) ? dinv[row] : 0.f;
  }
#pragma unroll
  for (int tt = 0; tt < 2; tt++) {
    int tcol = cg * 2 + tt;
    f32x4 acc = {0.f, 0.f, 0.f, 0.f};
#pragma unroll
    for (int c = 0; c < 4; c++) {
      bf16x8 bv = *(const bf16x8*)&Wt[(tcol * 16 + m) * WSTRIDE + c * 32 + q * 8];
      acc = __builtin_amdgcn_mfma_f32_16x16x32_bf16(a[c], bv, acc, 0, 0, 0);
    }
#pragma unroll
    for (int r = 0; r < 4; r++)
      if (rows[r] < N)
        to[(size_t)rows[r] * CDIM + tcol * 16 + m] = f2bf(acc[r] * sc4[r]);
  }
}

// ---------- layer-2 gather aggregation fused with mean-pool -------------------
// 16 consecutive nodes per wave (R4-proven shape).
__global__ __launch_bounds__(256) void k_aggp(const bf16_t* __restrict__ t,
    const int* __restrict__ rowptr, const int* __restrict__ col,
    const float* __restrict__ dinv, const float* __restrict__ bias,
    const int* __restrict__ batch, float* __restrict__ gsum, int N) {
  int wave = threadIdx.x >> 6;
  int lane = threadIdx.x & 63;
  int n0 = (blockIdx.x * 4 + wave) * 16;
  if (n0 >= N) return;
  int nEnd = n0 + 16; if (nEnd > N) nEnd = N;
  const unsigned* tp = (const unsigned*)t;
  float2 bb = ((const float2*)bias)[lane];
  float p0 = 0.f, p1 = 0.f;
  int curb = batch[n0];
  int sA[8]; unsigned vA[8];
  int sB[8]; unsigned vB[8];

  for (int node = n0; node < nEnd; node++) {
    float di = dinv[node];
    unsigned sv = tp[(size_t)node * 64 + lane];
    float a0 = bflo(sv);
    float a1 = bfhi(sv);
    int beg = rowptr[node], end = rowptr[node + 1];
    for (int base = beg; base < end; base += 64) {
      int cnt = end - base; if (cnt > 64) cnt = 64;
      int sL = N;
      if (lane < cnt) sL = col[base + lane];
      GBLOCK(cnt);
    }
    float o0 = fmaxf(fmaf(di, a0, bb.x), 0.f);
    float o1 = fmaxf(fmaf(di, a1, bb.y), 0.f);
    int b = batch[node];
    if (b != curb) {
      atomicAdd(&gsum[curb * CDIM + 2 * lane], p0);
      atomicAdd(&gsum[curb * CDIM + 2 * lane + 1], p1);
      curb = b; p0 = p1 = 0.f;
    }
    // keep bf16 rounding of h before pooling (parity with previous absmax)
    p0 += __uint_as_float((unsigned)f2bf(o0) << 16);
    p1 += __uint_as_float((unsigned)f2bf(o1) << 16);
  }
  atomicAdd(&gsum[curb * CDIM + 2 * lane], p0);
  atomicAdd(&gsum[curb * CDIM + 2 * lane + 1], p1);
}

// ---------- fused MLP head: pool-divide + mlp1 + mlp2 + mlp3 ------------------
__global__ __launch_bounds__(512) void k_mlp(const float* __restrict__ g,
    const int* __restrict__ batch, int N,
    const float* __restrict__ Wm1, const float* __restrict__ bm1,
    const float* __restrict__ Wm2, const float* __restrict__ bm2,
    const float* __restrict__ wm3, const float* __restrict__ bm3,
    float* __restrict__ out) {
  __shared__ float gs[CDIM];
  __shared__ float m1s[500];
  __shared__ float m2s[100];
  int bi = blockIdx.x, tid = threadIdx.x;
  if (tid < CDIM) {
    int lo = 0, hi = N;
    while (lo < hi) { int mid = (lo + hi) >> 1; if (batch[mid] < bi) lo = mid + 1; else hi = mid; }
    int s = lo;
    lo = 0; hi = N;
    int key = bi + 1;
    while (lo < hi) { int mid = (lo + hi) >> 1; if (batch[mid] < key) lo = mid + 1; else hi = mid; }
    float inv = 1.f / fmaxf((float)(lo - s), 1.f);
    gs[tid] = g[bi * CDIM + tid] * inv;
  }
  __syncthreads();
  if (tid < 500) {
    float acc = bm1[tid];
#pragma unroll 4
    for (int k = 0; k < CDIM; k++) acc = fmaf(gs[k], Wm1[k * 500 + tid], acc);
    m1s[tid] = fmaxf(acc, 0.f);
  }
  __syncthreads();
  if (tid < 100) {
    float acc = bm2[tid];
    for (int k = 0; k < 500; k++) acc = fmaf(m1s[k], Wm2[k * 100 + tid], acc);
    m2s[tid] = fmaxf(acc, 0.f) * wm3[tid];
  }
  __syncthreads();
  if (tid < 64) {
    float v = m2s[tid] + ((tid + 64 < 100) ? m2s[tid + 64] : 0.f);
#pragma unroll
    for (int ofs = 32; ofs > 0; ofs >>= 1) v += __shfl_down(v, ofs, 64);
    if (tid == 0) out[bi] = v + bm3[0];
  }
}

static inline size_t align_up(size_t v) { return (v + 255) & ~(size_t)255; }

extern "C" void kernel_launch(void* const* d_in, const int* in_sizes, int n_in,
                              void* d_out, int out_size, void* d_ws, size_t ws_size,
                              hipStream_t stream) {
  const float* x   = (const float*)d_in[0];
  const int*   ei  = (const int*)d_in[1];
  const int*   bat = (const int*)d_in[2];
  const float* W1  = (const float*)d_in[3];
  const float* b1  = (const float*)d_in[4];
  const float* W2  = (const float*)d_in[5];
  const float* b2  = (const float*)d_in[6];
  const float* Wm1 = (const float*)d_in[7];
  const float* bm1 = (const float*)d_in[8];
  const float* Wm2 = (const float*)d_in[9];
  const float* bm2 = (const float*)d_in[10];
  const float* Wm3 = (const float*)d_in[11];
  const float* bm3 = (const float*)d_in[12];
  float* out = (float*)d_out;

  const int E = in_sizes[1] / 2;
  const int N = in_sizes[2];
  const int* src = ei;
  const int* dst = ei + E;
  const int NB = (N + 127) >> BSH;
  const int M  = NB * NBLK;              // phist elements

  char* p = (char*)d_ws;
  bf16_t* t    = (bf16_t*)p;   p += align_up((size_t)(N + 1) * CDIM * 2);  // t1 (+zero row)
  bf16_t* t2   = (bf16_t*)p;   p += align_up((size_t)(N + 1) * CDIM * 2);  // t2 (+zero row)
  int* rowptr  = (int*)p;      p += align_up((size_t)(N + 1) * 4);
  int* colx    = (int*)p;      p += align_up((size_t)E * 4);
  unsigned* tmp= (unsigned*)p; p += align_up((size_t)E * 4);
  float* dinv  = (float*)p;    p += align_up((size_t)N * 4);
  int* phist   = (int*)p;      p += align_up((size_t)M * 4);
  int* btot    = (int*)p;      p += align_up((size_t)NB * 4);
  bf16_t* Wtg1 = (bf16_t*)p;   p += align_up((size_t)CDIM * CDIM * 2);
  bf16_t* Wtg2 = (bf16_t*)p;   p += align_up((size_t)CDIM * CDIM * 2);
  float* gb    = (float*)p;    p += align_up((size_t)NGRAPH * CDIM * 4);
  (void)ws_size; (void)n_in; (void)out_size;

  k_phist<<<NBLK, 1024, 0, stream>>>(dst, phist, W1, W2, Wtg1, Wtg2, gb, t, t2, N, E, NB);
  k_bscan<<<NB, 256, 0, stream>>>(phist, btot);
  k_pscatter<<<NBLK, 1024, 0, stream>>>(src, dst, phist, btot, tmp, E, NB);
  k_csort2<<<NB, 256, 0, stream>>>(tmp, btot, rowptr, dinv, colx, N, NB, E);

  k_gemm<0><<<1024, 256, 0, stream>>>(x, Wtg1, dinv, t, N);
  k_aggg<<<(N + 63) / 64, 1024, 0, stream>>>(t, rowptr, colx, dinv, b1, Wtg2, t2, N);
  int pwaves = (N + 15) / 16;
  k_aggp<<<(pwaves + 3) / 4, 256, 0, stream>>>(t2, rowptr, colx, dinv, b2, bat, gb, N);
  k_mlp<<<NGRAPH, 512, 0, stream>>>(gb, bat, N, Wm1, bm1, Wm2, bm2, Wm3, bm3, out);
}